// Round 4
// baseline (796.408 us; speedup 1.0000x reference)
//
#include <hip/hip_runtime.h>

// Problem constants (B=8, C=64, W=496, H=432)
#define WH      214272            // 496*432 pixels per (b,c) plane
#define GPB     53568             // WH/4 float4 groups per plane (mult of 64)
#define NGROUP  (8*GPB)           // (b, pixel/4) groups = 428544
#define TOTAL4  (512*GPB)         // all float4 elements = 27,426,816

#define STATS_BLOCKS 1024         // exactly 4 blocks/CU, uniform residency
#define SCALE_BLOCKS 2048

typedef float floatx4 __attribute__((ext_vector_type(4)));  // native vec: ok for nontemporal builtins

// ---------------- K1: per-channel sum / sumsq + per-batch mask count ----------------
// 4 waves/block; wave w owns channels [16w,16w+16). 32 accumulator VGPRs/thread.
// occ zeroes ALL channels of a pixel together -> wave 0's slice determines the mask.
// b is wave-uniform (stride and GPB are multiples of 64).
__global__ __launch_bounds__(256, 4) void k_stats(const floatx4* __restrict__ x4,
                                                  float* __restrict__ gsum,
                                                  float* __restrict__ gsq,
                                                  int* __restrict__ gn) {
    const int tid  = threadIdx.x;
    const int lane = tid & 63;
    const int wave = tid >> 6;
    const int c0   = wave * 16;

    float acc[16];
    float acc2[16];
#pragma unroll
    for (int j = 0; j < 16; ++j) { acc[j] = 0.f; acc2[j] = 0.f; }

    const int stride = STATS_BLOCKS * 64;
    for (int i = blockIdx.x * 64 + lane; i < NGROUP; i += stride) {
        const int b = (int)((unsigned)i / GPB);   // wave-uniform
        const int r = i - b * GPB;
        const floatx4* p = x4 + (size_t)(b * 64 + c0) * GPB + r;
        float sx = 0.f, sy = 0.f, sz = 0.f, sw = 0.f;
#pragma unroll
        for (int j = 0; j < 16; ++j) {
            const floatx4 v = p[(size_t)j * GPB];
            sx += v.x; sy += v.y; sz += v.z; sw += v.w;
            acc[j] += (v.x + v.y) + (v.z + v.w);
            acc2[j] = fmaf(v.w, v.w, fmaf(v.z, v.z, fmaf(v.y, v.y, fmaf(v.x, v.x, acc2[j]))));
        }
        if (wave == 0) {
            int cnt = (sx != 0.f) + (sy != 0.f) + (sz != 0.f) + (sw != 0.f);
#pragma unroll
            for (int m = 1; m < 64; m <<= 1) cnt += __shfl_xor(cnt, m, 64);
            if (lane == 0) atomicAdd(&gn[b], cnt);
        }
    }

    // butterfly-reduce each channel across the wave; lane j commits channel c0+j
    float mysum = 0.f, mysq = 0.f;
#pragma unroll
    for (int j = 0; j < 16; ++j) {
        float r1 = acc[j], r2 = acc2[j];
#pragma unroll
        for (int m = 1; m < 64; m <<= 1) {
            r1 += __shfl_xor(r1, m, 64);
            r2 += __shfl_xor(r2, m, 64);
        }
        if (lane == j) { mysum = r1; mysq = r2; }
    }
    if (lane < 16) {
        atomicAdd(&gsum[c0 + lane], mysum);
        atomicAdd(&gsq[c0 + lane], mysq);
    }
}

// ---------------- K2: finalize (per-block, ~free) + out = x * inv[c] ----------------
// Persistent grid-stride streaming kernel. Each block recomputes inv[64] into LDS
// from the 136-float stats (L2-resident after first block) -- kills the separate
// finalize launch. Plane index is wave-uniform (GPB % 64 == 0) -> sinv broadcast.
__global__ __launch_bounds__(256, 8) void k_scale(const floatx4* __restrict__ x4,
                                                  floatx4* __restrict__ out4,
                                                  const float* __restrict__ gsum,
                                                  const float* __restrict__ gsq,
                                                  const int* __restrict__ gn) {
    __shared__ float sinv[64];
    const int tid = threadIdx.x;
    if (tid < 64) {
        const int c = tid;
        const float* x = (const float*)x4;
        int nb[8];
        int N = 0;
#pragma unroll
        for (int b = 0; b < 8; ++b) { nb[b] = gn[b]; N = max(N, nb[b]); }
        float total = gsum[c];
        float S2    = gsq[c];
#pragma unroll
        for (int b = 0; b < 8; ++b) {
            const float pad = (float)(N - nb[b]);
            const float x00 = x[(size_t)(b * 64 + c) * WH];
            total = fmaf(pad, x00, total);
            S2    = fmaf(pad, x00 * x00, S2);
        }
        const float count = (float)(8 * N);
        const float mean  = total / count;
        const float var   = S2 / count - mean * mean;
        sinv[c] = 1.0f / sqrtf(var + 0.001f);
    }
    __syncthreads();

    const int nthreads = SCALE_BLOCKS * 256;
    for (int i = blockIdx.x * 256 + tid; i < TOTAL4; i += nthreads) {
        const int plane = (int)((unsigned)i / GPB);   // wave-uniform
        const float inv = sinv[plane & 63];
        floatx4 v = x4[i];
        v.x *= inv; v.y *= inv; v.z *= inv; v.w *= inv;
        __builtin_nontemporal_store(v, &out4[i]);     // write-once, skip cache pollution
    }
}

extern "C" void kernel_launch(void* const* d_in, const int* in_sizes, int n_in,
                              void* d_out, int out_size, void* d_ws, size_t ws_size,
                              hipStream_t stream) {
    const float* x  = (const float*)d_in[0];
    float* out      = (float*)d_out;
    float* wsf      = (float*)d_ws;
    float* gsum     = wsf;               // 64 floats
    float* gsq      = wsf + 64;          // 64 floats
    int*   gn       = (int*)(wsf + 128); // 8 ints

    (void)hipMemsetAsync(d_ws, 0, 136 * sizeof(float), stream);

    k_stats<<<STATS_BLOCKS, 256, 0, stream>>>((const floatx4*)x, gsum, gsq, gn);
    k_scale<<<SCALE_BLOCKS, 256, 0, stream>>>((const floatx4*)x, (floatx4*)out,
                                              gsum, gsq, gn);
}

// Round 5
// 791.808 us; speedup vs baseline: 1.0058x; 1.0058x over previous
//
#include <hip/hip_runtime.h>

// Problem constants (B=8, C=64, W=496, H=432)
#define WH      214272            // 496*432 pixels per (b,c) plane
#define GPB     53568             // WH/4 float4 groups per plane (mult of 64)
#define TOTAL4  (512*GPB)         // all float4 elements = 27,426,816
#define CHUNKS  (TOTAL4/64)       // 64-float4 (1 KB/wave) chunks = 428544
#define CPP     (GPB/64)          // chunks per plane = 837

#define STATS_BLOCKS 1024         // 4 blocks/CU
#define SCALE_BLOCKS 2048         // 8 blocks/CU, fully resident at <=64 VGPR

typedef float floatx4 __attribute__((ext_vector_type(4)));

// ---------------- K1: per-channel sum/sumsq + per-batch mask count ----------------
// Pure sequential streaming: each wave owns a contiguous run of 1KB chunks. Within
// a plane-run the channel is wave-uniform -> scalar register accumulators, butterfly
// reduce + 2 atomics per plane-run (<=3 runs/wave). Mask: occ zeroes all channels of
// a pixel together, so channel 0 alone determines it -> only c==0 planes count.
__global__ __launch_bounds__(256, 4) void k_stats(const floatx4* __restrict__ x4,
                                                  float* __restrict__ gsum,
                                                  float* __restrict__ gsq,
                                                  int* __restrict__ gn) {
    const int lane = threadIdx.x & 63;
    const int gw   = blockIdx.x * 4 + (threadIdx.x >> 6);   // global wave id
    const int nw   = STATS_BLOCKS * 4;
    const int per  = (CHUNKS + nw - 1) / nw;                // 105 chunks/wave
    int c0 = gw * per;
    const int c1 = min(c0 + per, CHUNKS);

    while (c0 < c1) {
        const int plane = (int)((unsigned)c0 / CPP);        // wave-uniform
        const int run   = min(c1, (plane + 1) * CPP);       // end of this plane-run
        const bool isC0 = (plane & 63) == 0;

        float s = 0.f, q = 0.f;
        int cnt = 0;
        const floatx4* p = x4 + (size_t)c0 * 64 + lane;
        const int n = run - c0;
#pragma unroll 4
        for (int k = 0; k < n; ++k) {
            const floatx4 v = p[(size_t)k * 64];
            s += (v.x + v.y) + (v.z + v.w);
            q = fmaf(v.w, v.w, fmaf(v.z, v.z, fmaf(v.y, v.y, fmaf(v.x, v.x, q))));
            if (isC0) cnt += (v.x != 0.f) + (v.y != 0.f) + (v.z != 0.f) + (v.w != 0.f);
        }
#pragma unroll
        for (int m = 1; m < 64; m <<= 1) {
            s += __shfl_xor(s, m, 64);
            q += __shfl_xor(q, m, 64);
        }
        if (isC0) {
#pragma unroll
            for (int m = 1; m < 64; m <<= 1) cnt += __shfl_xor(cnt, m, 64);
        }
        if (lane == 0) {
            atomicAdd(&gsum[plane & 63], s);
            atomicAdd(&gsq[plane & 63], q);
            if (isC0) atomicAdd(&gn[plane >> 6], cnt);
        }
        c0 = run;
    }
}

// ---------------- K2: finalize (prologue) + out = x * inv[c], REVERSE order ----------
// k_stats streamed x forward, so the tail ~256MB of x is L3-resident. Walking chunks
// in reverse farms those as L3 hits. NT loads/stores: x won't be re-read, out is
// write-once -> don't displace the resident tail.
__global__ __launch_bounds__(256, 8) void k_scale(const floatx4* __restrict__ x4,
                                                  floatx4* __restrict__ out4,
                                                  const float* __restrict__ gsum,
                                                  const float* __restrict__ gsq,
                                                  const int* __restrict__ gn) {
    __shared__ float sinv[64];
    const int tid = threadIdx.x;
    if (tid < 64) {
        const int c = tid;
        const float* x = (const float*)x4;
        int nb[8];
        int N = 0;
#pragma unroll
        for (int b = 0; b < 8; ++b) { nb[b] = gn[b]; N = max(N, nb[b]); }
        float total = gsum[c];
        float S2    = gsq[c];
#pragma unroll
        for (int b = 0; b < 8; ++b) {
            const float pad = (float)(N - nb[b]);
            const float x00 = x[(size_t)(b * 64 + c) * WH];
            total = fmaf(pad, x00, total);
            S2    = fmaf(pad, x00 * x00, S2);
        }
        const float count = (float)(8 * N);
        const float mean  = total / count;
        const float var   = S2 / count - mean * mean;
        sinv[c] = 1.0f / sqrtf(var + 0.001f);
    }
    __syncthreads();

    const int lane = tid & 63;
    const int gw   = blockIdx.x * 4 + (tid >> 6);   // 0..8191
    const int nw   = SCALE_BLOCKS * 4;
#pragma unroll 2
    for (int ch = CHUNKS - 1 - gw; ch >= 0; ch -= nw) {
        const int plane = (int)((unsigned)ch / CPP);      // wave-uniform
        const float inv = sinv[plane & 63];
        const size_t i = (size_t)ch * 64 + lane;
        floatx4 v = __builtin_nontemporal_load(&x4[i]);
        v.x *= inv; v.y *= inv; v.z *= inv; v.w *= inv;
        __builtin_nontemporal_store(v, &out4[i]);
    }
}

extern "C" void kernel_launch(void* const* d_in, const int* in_sizes, int n_in,
                              void* d_out, int out_size, void* d_ws, size_t ws_size,
                              hipStream_t stream) {
    const float* x  = (const float*)d_in[0];
    float* out      = (float*)d_out;
    float* wsf      = (float*)d_ws;
    float* gsum     = wsf;               // 64 floats
    float* gsq      = wsf + 64;          // 64 floats
    int*   gn       = (int*)(wsf + 128); // 8 ints

    (void)hipMemsetAsync(d_ws, 0, 136 * sizeof(float), stream);

    k_stats<<<STATS_BLOCKS, 256, 0, stream>>>((const floatx4*)x, gsum, gsq, gn);
    k_scale<<<SCALE_BLOCKS, 256, 0, stream>>>((const floatx4*)x, (floatx4*)out,
                                              gsum, gsq, gn);
}